// Round 2
// baseline (537.470 us; speedup 1.0000x reference)
//
#include <hip/hip_runtime.h>

#define HH 192
#define WW 192
#define CC 64
#define NB 1024
#define SS 32

typedef __bf16 bf16x8 __attribute__((ext_vector_type(8)));
typedef float  f32x4  __attribute__((ext_vector_type(4)));

__device__ __forceinline__ float bf2f(unsigned short u) {
    unsigned int v = ((unsigned int)u) << 16;
    return __builtin_bit_cast(float, v);
}
__device__ __forceinline__ unsigned short f2bf(float f) {
    unsigned int u = __builtin_bit_cast(unsigned int, f);
    u += 0x7FFFu + ((u >> 16) & 1u);   // round-to-nearest-even
    return (unsigned short)(u >> 16);
}
__device__ __forceinline__ float lo16(unsigned int u) {
    return __builtin_bit_cast(float, u << 16);
}
__device__ __forceinline__ float hi16(unsigned int u) {
    return __builtin_bit_cast(float, u & 0xFFFF0000u);
}

// ---------------------------------------------------------------------------
// Weight pre-transpose: w f32 [tap][c][o] (tap=dy*3+dx, 64x64) -> bf16
// WT[tap][kc][nt][lane][j]  with c = kc*32 + (lane>>4)*8 + j, o = nt*16 + (lane&15)
// so a b-fragment load is one coalesced 16B read per lane.
// ---------------------------------------------------------------------------
__global__ __launch_bounds__(256) void wt_kernel(const float* __restrict__ w,
                                                 unsigned short* __restrict__ wt) {
    int idx = blockIdx.x * 256 + threadIdx.x;      // 0 .. 36863
    int j    = idx & 7;
    int lane = (idx >> 3) & 63;
    int nt   = (idx >> 9) & 3;
    int kc   = (idx >> 11) & 1;
    int tap  = idx >> 12;
    int c = kc * 32 + ((lane >> 4) << 3) + j;
    int o = (nt << 4) + (lane & 15);
    wt[idx] = f2bf(w[(tap * 64 + c) * 64 + o]);
}

// ---------------------------------------------------------------------------
// Crop & resize (bilinear) from f32 features -> bf16 [Nc][32][32][64].
// One block per (box, row).
// ---------------------------------------------------------------------------
__global__ __launch_bounds__(256) void crop_kernel(const float* __restrict__ feat,
                                                   const float* __restrict__ boxes,
                                                   const int* __restrict__ box_ids,
                                                   unsigned short* __restrict__ out, int n0) {
    int blk = blockIdx.x;
    int nl  = blk >> 5;          // local box index
    int y   = blk & 31;
    int gn  = n0 + nl;
    int t   = threadIdx.x;
    int px  = t >> 3;            // x within crop, 0..31
    int c0  = (t & 7) << 3;      // channel group (8 floats)

    float by1 = boxes[gn * 4 + 0];
    float bx1 = boxes[gn * 4 + 1];
    float by2 = boxes[gn * 4 + 2];
    float bx2 = boxes[gn * 4 + 3];

    float ty = (float)y  / 31.0f;
    float tx = (float)px / 31.0f;
    float ys = (by1 + ty * (by2 - by1)) * 191.0f;
    float xs = (bx1 + tx * (bx2 - bx1)) * 191.0f;
    float y0f = fminf(fmaxf(floorf(ys), 0.0f), 191.0f);
    float x0f = fminf(fmaxf(floorf(xs), 0.0f), 191.0f);
    float wy = ys - y0f, wx = xs - x0f;
    int y0i = (int)y0f, x0i = (int)x0f;
    int y1i = min(y0i + 1, 191), x1i = min(x0i + 1, 191);

    const float* fb = feat + (size_t)box_ids[gn] * (HH * WW * CC);
    const float* p00 = fb + ((size_t)y0i * WW + x0i) * CC + c0;
    const float* p01 = fb + ((size_t)y0i * WW + x1i) * CC + c0;
    const float* p10 = fb + ((size_t)y1i * WW + x0i) * CC + c0;
    const float* p11 = fb + ((size_t)y1i * WW + x1i) * CC + c0;

    unsigned int r[4];
#pragma unroll
    for (int h = 0; h < 2; h++) {
        float4 v00 = *(const float4*)(p00 + 4 * h);
        float4 v01 = *(const float4*)(p01 + 4 * h);
        float4 v10 = *(const float4*)(p10 + 4 * h);
        float4 v11 = *(const float4*)(p11 + 4 * h);
        const float* a00 = (const float*)&v00;
        const float* a01 = (const float*)&v01;
        const float* a10 = (const float*)&v10;
        const float* a11 = (const float*)&v11;
#pragma unroll
        for (int i = 0; i < 4; i++) {
            float top = a00[i] + wx * (a01[i] - a00[i]);
            float bot = a10[i] + wx * (a11[i] - a10[i]);
            float v = top + wy * (bot - top);
            unsigned short b = f2bf(v);
            int e = 4 * h + i;            // element 0..7
            if (e & 1) r[e >> 1] |= ((unsigned int)b << 16);
            else       r[e >> 1]  = (unsigned int)b;
        }
    }
    *(uint4*)(out + (((size_t)nl * 32 + y) * 32 + px) * CC + c0) = *(uint4*)r;
}

// ---------------------------------------------------------------------------
// 3x3 SAME conv, 64->64 ch, + ReLU, bf16 in/out, f32 accum via MFMA 16x16x32.
// Block: one box x 8-row tile. 4 waves; wave w computes rows 2w,2w+1 (64 px) x 64 oc.
// LDS input tile [10 rows][32 px][64 ch], x-stride padded to 72 elems.
// Weights read from pre-transposed global WT (L2-resident, coalesced 16B/lane).
// ---------------------------------------------------------------------------
__global__ __launch_bounds__(256, 3) void conv3x3_kernel(const unsigned short* __restrict__ in,
                                                         const unsigned short* __restrict__ wt,
                                                         const float* __restrict__ bias,
                                                         unsigned short* __restrict__ out) {
    __shared__ unsigned short s_in[10 * 32 * 72];   // 46080 B

    int nl = blockIdx.y;
    int y0 = blockIdx.x << 3;
    int t = threadIdx.x;
    int wave = t >> 6, lane = t & 63;
    int quad = lane >> 4, mcol = lane & 15;

    // stage input rows y0-1 .. y0+8 (zero rows outside [0,32))
    {
        int px = t >> 3, cc = (t & 7) << 3;
        const unsigned short* src = in + (((size_t)nl * 32) * 32 + px) * 64 + cc;
#pragma unroll
        for (int r = 0; r < 10; r++) {
            int gy = y0 + r - 1;
            uint4 v = {0, 0, 0, 0};
            if (gy >= 0 && gy < 32) v = *(const uint4*)(src + (size_t)gy * 32 * 64);
            *(uint4*)(s_in + (r * 32 + px) * 72 + cc) = v;
        }
    }
    __syncthreads();

    f32x4 acc[4][4];
#pragma unroll
    for (int nt = 0; nt < 4; nt++) {
        float bv = bias[(nt << 4) + mcol];
#pragma unroll
        for (int mi = 0; mi < 4; mi++) acc[mi][nt] = (f32x4){bv, bv, bv, bv};
    }

    int r0 = wave << 1;
#pragma unroll
    for (int dy = 0; dy < 3; dy++) {
#pragma unroll
        for (int dx = 0; dx < 3; dx++) {
            int tap = dy * 3 + dx;
#pragma unroll
            for (int kc = 0; kc < 2; kc++) {
                uint4 bfr[4];
#pragma unroll
                for (int nt = 0; nt < 4; nt++)
                    bfr[nt] = *(const uint4*)(wt + ((((tap * 2 + kc) * 4 + nt) * 64 + lane) << 3));
                uint4 afr[4];
#pragma unroll
                for (int mi = 0; mi < 4; mi++) {
                    int xs = ((mi & 1) << 4) + mcol + dx - 1;
                    uint4 a = {0, 0, 0, 0};
                    if (xs >= 0 && xs < 32)
                        a = *(const uint4*)(s_in + ((r0 + (mi >> 1) + dy) * 32 + xs) * 72 +
                                            (kc << 5) + (quad << 3));
                    afr[mi] = a;
                }
#pragma unroll
                for (int mi = 0; mi < 4; mi++)
#pragma unroll
                    for (int nt = 0; nt < 4; nt++)
                        acc[mi][nt] = __builtin_amdgcn_mfma_f32_16x16x32_bf16(
                            __builtin_bit_cast(bf16x8, afr[mi]),
                            __builtin_bit_cast(bf16x8, bfr[nt]), acc[mi][nt], 0, 0, 0);
            }
        }
    }

    // epilogue: D element (m = quad*4+reg, oc = nt*16 + mcol); ReLU; bf16 store
#pragma unroll
    for (int mi = 0; mi < 4; mi++) {
        int yy = y0 + r0 + (mi >> 1);
        int xb = ((mi & 1) << 4) + (quad << 2);
#pragma unroll
        for (int reg = 0; reg < 4; reg++) {
            unsigned short* op = out + (((size_t)nl * 32 + yy) * 32 + (xb + reg)) * 64 + mcol;
#pragma unroll
            for (int nt = 0; nt < 4; nt++) {
                float v = fmaxf(acc[mi][nt][reg], 0.0f);
                op[nt << 4] = f2bf(v);
            }
        }
    }
}

// ---------------------------------------------------------------------------
// Final 3x3 VALID conv, only the selected class channel.
// in: bf16 [nc][32][32][64]; weights f32; out f32 [N][30][30]
// ---------------------------------------------------------------------------
__global__ __launch_bounds__(256) void outconv_kernel(const unsigned short* __restrict__ in,
                                                      const float* __restrict__ ow,
                                                      const float* __restrict__ ob,
                                                      const int* __restrict__ cls,
                                                      float* __restrict__ out, int n0) {
    __shared__ float s_w[576];
    int nl = blockIdx.x;
    int gn = n0 + nl;
    int oc = cls[gn];
    int t = threadIdx.x;
    for (int i = t; i < 576; i += 256) s_w[i] = ow[i * 3 + oc];
    __syncthreads();
    float bias = ob[oc];
    const unsigned short* base = in + (size_t)nl * 32 * 32 * 64;
    for (int px = t; px < 900; px += 256) {
        int y = px / 30, x = px - y * 30;
        float acc = bias;
#pragma unroll
        for (int dy = 0; dy < 3; dy++) {
#pragma unroll
            for (int dx = 0; dx < 3; dx++) {
                const unsigned short* p = base + (((y + dy) * 32) + (x + dx)) * 64;
                const float* wp = s_w + (dy * 3 + dx) * 64;
#pragma unroll
                for (int c8 = 0; c8 < 8; c8++) {
                    uint4 v = *(const uint4*)(p + (c8 << 3));
                    const unsigned int* vv = (const unsigned int*)&v;
#pragma unroll
                    for (int i = 0; i < 4; i++) {
                        acc = fmaf(lo16(vv[i]), wp[(c8 << 3) + i * 2], acc);
                        acc = fmaf(hi16(vv[i]), wp[(c8 << 3) + i * 2 + 1], acc);
                    }
                }
            }
        }
        out[(size_t)gn * 900 + px] = acc;
    }
}

// ---------------------------------------------------------------------------
extern "C" void kernel_launch(void* const* d_in, const int* in_sizes, int n_in,
                              void* d_out, int out_size, void* d_ws, size_t ws_size,
                              hipStream_t stream) {
    const float* feat    = (const float*)d_in[0];
    const float* boxes   = (const float*)d_in[1];
    const int*   box_ids = (const int*)d_in[2];
    const int*   cls     = (const int*)d_in[3];
    const float* c1w     = (const float*)d_in[4];
    const float* c1b     = (const float*)d_in[5];
    const float* c2w     = (const float*)d_in[6];
    const float* c2b     = (const float*)d_in[7];
    const float* ow      = (const float*)d_in[8];
    const float* ob      = (const float*)d_in[9];

    unsigned short* wt1  = (unsigned short*)d_ws;
    unsigned short* wt2  = wt1 + 36864;
    unsigned short* bufs = wt2 + 36864;

    // chunk boxes so two bf16 [nc][32][32][64] buffers fit in ws (deterministic)
    size_t wt_bytes = (size_t)2 * 36864 * 2;
    size_t avail = (ws_size > wt_bytes) ? (ws_size - wt_bytes) / 2 : 0;
    size_t per_box = (size_t)32 * 32 * 64 * 2;
    int nc = (int)(avail / per_box);
    if (nc >= NB) nc = NB;
    else {
        int p = 1;
        while (p * 2 <= nc) p *= 2;
        nc = (p < 1) ? 1 : p;
    }

    wt_kernel<<<144, 256, 0, stream>>>(c1w, wt1);
    wt_kernel<<<144, 256, 0, stream>>>(c2w, wt2);

    unsigned short* bufA = bufs;
    unsigned short* bufB = bufs + (size_t)nc * 65536;

    for (int nn0 = 0; nn0 < NB; nn0 += nc) {
        int cur = (NB - nn0 < nc) ? (NB - nn0) : nc;
        crop_kernel<<<cur * 32, 256, 0, stream>>>(feat, boxes, box_ids, bufA, nn0);
        conv3x3_kernel<<<dim3(4, cur), 256, 0, stream>>>(bufA, wt1, c1b, bufB);
        conv3x3_kernel<<<dim3(4, cur), 256, 0, stream>>>(bufB, wt2, c2b, bufA);
        outconv_kernel<<<cur, 256, 0, stream>>>(bufA, ow, ob, cls, (float*)d_out, nn0);
    }
}

// Round 3
// 517.922 us; speedup vs baseline: 1.0377x; 1.0377x over previous
//
#include <hip/hip_runtime.h>

#define HH 192
#define WW 192
#define CC 64
#define NB 1024
#define SS 32

typedef __bf16 bf16x8 __attribute__((ext_vector_type(8)));
typedef float  f32x4  __attribute__((ext_vector_type(4)));

__device__ __forceinline__ float bf2f(unsigned short u) {
    unsigned int v = ((unsigned int)u) << 16;
    return __builtin_bit_cast(float, v);
}
__device__ __forceinline__ unsigned short f2bf(float f) {
    unsigned int u = __builtin_bit_cast(unsigned int, f);
    u += 0x7FFFu + ((u >> 16) & 1u);   // round-to-nearest-even
    return (unsigned short)(u >> 16);
}
__device__ __forceinline__ float lo16(unsigned int u) {
    return __builtin_bit_cast(float, u << 16);
}
__device__ __forceinline__ float hi16(unsigned int u) {
    return __builtin_bit_cast(float, u & 0xFFFF0000u);
}

// ---------------------------------------------------------------------------
// Weight pre-transpose: w f32 [tap][c][o] (tap=dy*3+dx, 64x64) -> bf16
// WT[tap][kc][nt][lane][j]  with c = kc*32 + (lane>>4)*8 + j, o = nt*16 + (lane&15)
// so a b-fragment load is one coalesced 16B read per lane.
// ---------------------------------------------------------------------------
__global__ __launch_bounds__(256) void wt_kernel(const float* __restrict__ w,
                                                 unsigned short* __restrict__ wt) {
    int idx = blockIdx.x * 256 + threadIdx.x;      // 0 .. 36863
    int j    = idx & 7;
    int lane = (idx >> 3) & 63;
    int nt   = (idx >> 9) & 3;
    int kc   = (idx >> 11) & 1;
    int tap  = idx >> 12;
    int c = kc * 32 + ((lane >> 4) << 3) + j;
    int o = (nt << 4) + (lane & 15);
    wt[idx] = f2bf(w[(tap * 64 + c) * 64 + o]);
}

// ---------------------------------------------------------------------------
// Crop & resize (bilinear) from f32 features -> bf16 [Nc][32][32][64].
// One block per (box, row).
// ---------------------------------------------------------------------------
__global__ __launch_bounds__(256) void crop_kernel(const float* __restrict__ feat,
                                                   const float* __restrict__ boxes,
                                                   const int* __restrict__ box_ids,
                                                   unsigned short* __restrict__ out, int n0) {
    int blk = blockIdx.x;
    int nl  = blk >> 5;          // local box index
    int y   = blk & 31;
    int gn  = n0 + nl;
    int t   = threadIdx.x;
    int px  = t >> 3;            // x within crop, 0..31
    int c0  = (t & 7) << 3;      // channel group (8 floats)

    float by1 = boxes[gn * 4 + 0];
    float bx1 = boxes[gn * 4 + 1];
    float by2 = boxes[gn * 4 + 2];
    float bx2 = boxes[gn * 4 + 3];

    float ty = (float)y  / 31.0f;
    float tx = (float)px / 31.0f;
    float ys = (by1 + ty * (by2 - by1)) * 191.0f;
    float xs = (bx1 + tx * (bx2 - bx1)) * 191.0f;
    float y0f = fminf(fmaxf(floorf(ys), 0.0f), 191.0f);
    float x0f = fminf(fmaxf(floorf(xs), 0.0f), 191.0f);
    float wy = ys - y0f, wx = xs - x0f;
    int y0i = (int)y0f, x0i = (int)x0f;
    int y1i = min(y0i + 1, 191), x1i = min(x0i + 1, 191);

    const float* fb = feat + (size_t)box_ids[gn] * (HH * WW * CC);
    const float* p00 = fb + ((size_t)y0i * WW + x0i) * CC + c0;
    const float* p01 = fb + ((size_t)y0i * WW + x1i) * CC + c0;
    const float* p10 = fb + ((size_t)y1i * WW + x0i) * CC + c0;
    const float* p11 = fb + ((size_t)y1i * WW + x1i) * CC + c0;

    unsigned int r[4];
#pragma unroll
    for (int h = 0; h < 2; h++) {
        float4 v00 = *(const float4*)(p00 + 4 * h);
        float4 v01 = *(const float4*)(p01 + 4 * h);
        float4 v10 = *(const float4*)(p10 + 4 * h);
        float4 v11 = *(const float4*)(p11 + 4 * h);
        const float* a00 = (const float*)&v00;
        const float* a01 = (const float*)&v01;
        const float* a10 = (const float*)&v10;
        const float* a11 = (const float*)&v11;
#pragma unroll
        for (int i = 0; i < 4; i++) {
            float top = a00[i] + wx * (a01[i] - a00[i]);
            float bot = a10[i] + wx * (a11[i] - a10[i]);
            float v = top + wy * (bot - top);
            unsigned short b = f2bf(v);
            int e = 4 * h + i;            // element 0..7
            if (e & 1) r[e >> 1] |= ((unsigned int)b << 16);
            else       r[e >> 1]  = (unsigned int)b;
        }
    }
    *(uint4*)(out + (((size_t)nl * 32 + y) * 32 + px) * CC + c0) = *(uint4*)r;
}

// ---------------------------------------------------------------------------
// 3x3 SAME conv, 64->64 ch, + ReLU, bf16 in/out, f32 accum via MFMA 16x16x32.
// Block: one box x 8-row tile. 4 waves; wave w computes rows 2w,2w+1 (64 px) x 64 oc.
// LDS input tile [10 rows][32 px][64 ch], x-stride padded to 72 elems.
// Weights read from pre-transposed global WT (L2-resident, coalesced 16B/lane).
// ---------------------------------------------------------------------------
__global__ __launch_bounds__(256, 3) void conv3x3_kernel(const unsigned short* __restrict__ in,
                                                         const unsigned short* __restrict__ wt,
                                                         const float* __restrict__ bias,
                                                         unsigned short* __restrict__ out) {
    __shared__ unsigned short s_in[10 * 32 * 72];   // 46080 B

    int nl = blockIdx.y;
    int y0 = blockIdx.x << 3;
    int t = threadIdx.x;
    int wave = t >> 6, lane = t & 63;
    int quad = lane >> 4, mcol = lane & 15;

    // stage input rows y0-1 .. y0+8 (zero rows outside [0,32))
    {
        int px = t >> 3, cc = (t & 7) << 3;
        const unsigned short* src = in + (((size_t)nl * 32) * 32 + px) * 64 + cc;
#pragma unroll
        for (int r = 0; r < 10; r++) {
            int gy = y0 + r - 1;
            uint4 v = {0, 0, 0, 0};
            if (gy >= 0 && gy < 32) v = *(const uint4*)(src + (size_t)gy * 32 * 64);
            *(uint4*)(s_in + (r * 32 + px) * 72 + cc) = v;
        }
    }
    __syncthreads();

    f32x4 acc[4][4];
#pragma unroll
    for (int nt = 0; nt < 4; nt++) {
        float bv = bias[(nt << 4) + mcol];
#pragma unroll
        for (int mi = 0; mi < 4; mi++) acc[mi][nt] = (f32x4){bv, bv, bv, bv};
    }

    int r0 = wave << 1;
#pragma unroll
    for (int dy = 0; dy < 3; dy++) {
#pragma unroll
        for (int dx = 0; dx < 3; dx++) {
            int tap = dy * 3 + dx;
#pragma unroll
            for (int kc = 0; kc < 2; kc++) {
                uint4 bfr[4];
#pragma unroll
                for (int nt = 0; nt < 4; nt++)
                    bfr[nt] = *(const uint4*)(wt + ((((tap * 2 + kc) * 4 + nt) * 64 + lane) << 3));
                uint4 afr[4];
#pragma unroll
                for (int mi = 0; mi < 4; mi++) {
                    int xs = ((mi & 1) << 4) + mcol + dx - 1;
                    uint4 a = {0, 0, 0, 0};
                    if (xs >= 0 && xs < 32)
                        a = *(const uint4*)(s_in + ((r0 + (mi >> 1) + dy) * 32 + xs) * 72 +
                                            (kc << 5) + (quad << 3));
                    afr[mi] = a;
                }
#pragma unroll
                for (int mi = 0; mi < 4; mi++)
#pragma unroll
                    for (int nt = 0; nt < 4; nt++)
                        acc[mi][nt] = __builtin_amdgcn_mfma_f32_16x16x32_bf16(
                            __builtin_bit_cast(bf16x8, afr[mi]),
                            __builtin_bit_cast(bf16x8, bfr[nt]), acc[mi][nt], 0, 0, 0);
            }
        }
    }

    // epilogue: D element (m = quad*4+reg, oc = nt*16 + mcol); ReLU; bf16 store
#pragma unroll
    for (int mi = 0; mi < 4; mi++) {
        int yy = y0 + r0 + (mi >> 1);
        int xb = ((mi & 1) << 4) + (quad << 2);
#pragma unroll
        for (int reg = 0; reg < 4; reg++) {
            unsigned short* op = out + (((size_t)nl * 32 + yy) * 32 + (xb + reg)) * 64 + mcol;
#pragma unroll
            for (int nt = 0; nt < 4; nt++) {
                float v = fmaxf(acc[mi][nt][reg], 0.0f);
                op[nt << 4] = f2bf(v);
            }
        }
    }
}

// ---------------------------------------------------------------------------
// Final 3x3 VALID conv, only the selected class channel.
// in: bf16 [nc][32][32][64]; weights f32; out f32 [N][30][30]
// Block = (box, 8-row strip); 1 thread per output px; 8 independent acc chains.
// ---------------------------------------------------------------------------
__global__ __launch_bounds__(256) void outconv_kernel(const unsigned short* __restrict__ in,
                                                      const float* __restrict__ ow,
                                                      const float* __restrict__ ob,
                                                      const int* __restrict__ cls,
                                                      float* __restrict__ out, int n0) {
    __shared__ float s_w[576];
    int nl = blockIdx.x;
    int gn = n0 + nl;
    int oc = cls[gn];
    int t = threadIdx.x;
    for (int i = t; i < 576; i += 256) s_w[i] = ow[i * 3 + oc];
    __syncthreads();

    int r0 = blockIdx.y << 3;            // strip start row (0,8,16,24)
    int y  = r0 + (t >> 5) ;             // t/32 -> wait, 30 px per row; use div
    // pixel mapping: local px index t in [0,240): y = r0 + t/30, x = t%30
    int py = t / 30;
    int px = t - py * 30;
    y = r0 + py;
    if (t < 240 && y < 30) {
        const unsigned short* base = in + (size_t)nl * 32 * 32 * 64;
        float a[8];
#pragma unroll
        for (int c8 = 0; c8 < 8; c8++) a[c8] = 0.0f;
#pragma unroll
        for (int dy = 0; dy < 3; dy++) {
#pragma unroll
            for (int dx = 0; dx < 3; dx++) {
                const unsigned short* p = base + (((y + dy) * 32) + (px + dx)) * 64;
                const float* wp = s_w + (dy * 3 + dx) * 64;
#pragma unroll
                for (int c8 = 0; c8 < 8; c8++) {
                    uint4 v = *(const uint4*)(p + (c8 << 3));
                    const unsigned int* vv = (const unsigned int*)&v;
#pragma unroll
                    for (int i = 0; i < 4; i++) {
                        a[c8] = fmaf(lo16(vv[i]), wp[(c8 << 3) + i * 2], a[c8]);
                        a[c8] = fmaf(hi16(vv[i]), wp[(c8 << 3) + i * 2 + 1], a[c8]);
                    }
                }
            }
        }
        float acc = ob[oc];
#pragma unroll
        for (int c8 = 0; c8 < 8; c8++) acc += a[c8];
        out[(size_t)gn * 900 + y * 30 + px] = acc;
    }
}

// ---------------------------------------------------------------------------
extern "C" void kernel_launch(void* const* d_in, const int* in_sizes, int n_in,
                              void* d_out, int out_size, void* d_ws, size_t ws_size,
                              hipStream_t stream) {
    const float* feat    = (const float*)d_in[0];
    const float* boxes   = (const float*)d_in[1];
    const int*   box_ids = (const int*)d_in[2];
    const int*   cls     = (const int*)d_in[3];
    const float* c1w     = (const float*)d_in[4];
    const float* c1b     = (const float*)d_in[5];
    const float* c2w     = (const float*)d_in[6];
    const float* c2b     = (const float*)d_in[7];
    const float* ow      = (const float*)d_in[8];
    const float* ob      = (const float*)d_in[9];

    unsigned short* wt1  = (unsigned short*)d_ws;
    unsigned short* wt2  = wt1 + 36864;
    unsigned short* bufs = wt2 + 36864;

    // chunk boxes so two bf16 [nc][32][32][64] buffers fit in ws (deterministic)
    size_t wt_bytes = (size_t)2 * 36864 * 2;
    size_t avail = (ws_size > wt_bytes) ? (ws_size - wt_bytes) / 2 : 0;
    size_t per_box = (size_t)32 * 32 * 64 * 2;
    int nc = (int)(avail / per_box);
    if (nc >= NB) nc = NB;
    else {
        int p = 1;
        while (p * 2 <= nc) p *= 2;
        nc = (p < 1) ? 1 : p;
    }

    wt_kernel<<<144, 256, 0, stream>>>(c1w, wt1);
    wt_kernel<<<144, 256, 0, stream>>>(c2w, wt2);

    unsigned short* bufA = bufs;
    unsigned short* bufB = bufs + (size_t)nc * 65536;

    for (int nn0 = 0; nn0 < NB; nn0 += nc) {
        int cur = (NB - nn0 < nc) ? (NB - nn0) : nc;
        crop_kernel<<<cur * 32, 256, 0, stream>>>(feat, boxes, box_ids, bufA, nn0);
        conv3x3_kernel<<<dim3(4, cur), 256, 0, stream>>>(bufA, wt1, c1b, bufB);
        conv3x3_kernel<<<dim3(4, cur), 256, 0, stream>>>(bufB, wt2, c2b, bufA);
        outconv_kernel<<<dim3(cur, 4), 256, 0, stream>>>(bufA, ow, ob, cls, (float*)d_out, nn0);
    }
}

// Round 4
// 435.467 us; speedup vs baseline: 1.2342x; 1.1893x over previous
//
#include <hip/hip_runtime.h>

#define HH 192
#define WW 192
#define CC 64
#define NB 1024
#define SS 32

typedef __bf16 bf16x8 __attribute__((ext_vector_type(8)));
typedef float  f32x4  __attribute__((ext_vector_type(4)));

__device__ __forceinline__ float bf2f(unsigned short u) {
    unsigned int v = ((unsigned int)u) << 16;
    return __builtin_bit_cast(float, v);
}
__device__ __forceinline__ unsigned short f2bf(float f) {
    unsigned int u = __builtin_bit_cast(unsigned int, f);
    u += 0x7FFFu + ((u >> 16) & 1u);   // round-to-nearest-even
    return (unsigned short)(u >> 16);
}
__device__ __forceinline__ float lo16(unsigned int u) {
    return __builtin_bit_cast(float, u << 16);
}
__device__ __forceinline__ float hi16(unsigned int u) {
    return __builtin_bit_cast(float, u & 0xFFFF0000u);
}

// ---------------------------------------------------------------------------
// Weight pre-transpose: w f32 [tap][c][o] (tap=dy*3+dx, 64x64) -> bf16
// WT[tap][kc][nt][lane][j]  with c = kc*32 + (lane>>4)*8 + j, o = nt*16 + (lane&15)
// so a b-fragment load is one coalesced 16B read per lane.
// ---------------------------------------------------------------------------
__global__ __launch_bounds__(256) void wt_kernel(const float* __restrict__ w,
                                                 unsigned short* __restrict__ wt) {
    int idx = blockIdx.x * 256 + threadIdx.x;      // 0 .. 36863
    int j    = idx & 7;
    int lane = (idx >> 3) & 63;
    int nt   = (idx >> 9) & 3;
    int kc   = (idx >> 11) & 1;
    int tap  = idx >> 12;
    int c = kc * 32 + ((lane >> 4) << 3) + j;
    int o = (nt << 4) + (lane & 15);
    wt[idx] = f2bf(w[(tap * 64 + c) * 64 + o]);
}

// ---------------------------------------------------------------------------
// Out-weight transpose: ow f32 [tap][c][3] -> bf16 B-frag layout, cols padded
// to 16: WTo[tap][kc][lane][j], k = kc*32 + (lane>>4)*8 + j, col = lane&15
// (only cols 0..2 nonzero). 18*64*8 = 9216 elems.
// ---------------------------------------------------------------------------
__global__ __launch_bounds__(256) void wto_kernel(const float* __restrict__ ow,
                                                  unsigned short* __restrict__ wto) {
    int idx = blockIdx.x * 256 + threadIdx.x;      // 0 .. 9215
    int j    = idx & 7;
    int lane = (idx >> 3) & 63;
    int kc   = (idx >> 9) & 1;
    int tap  = idx >> 10;
    int c = kc * 32 + ((lane >> 4) << 3) + j;
    int o = lane & 15;
    wto[idx] = (o < 3) ? f2bf(ow[(tap * 64 + c) * 3 + o]) : (unsigned short)0;
}

// ---------------------------------------------------------------------------
// Crop & resize (bilinear) from f32 features -> bf16 [Nc][32][32][64].
// One block per (box, row).
// ---------------------------------------------------------------------------
__global__ __launch_bounds__(256) void crop_kernel(const float* __restrict__ feat,
                                                   const float* __restrict__ boxes,
                                                   const int* __restrict__ box_ids,
                                                   unsigned short* __restrict__ out, int n0) {
    int blk = blockIdx.x;
    int nl  = blk >> 5;          // local box index
    int y   = blk & 31;
    int gn  = n0 + nl;
    int t   = threadIdx.x;
    int px  = t >> 3;            // x within crop, 0..31
    int c0  = (t & 7) << 3;      // channel group (8 floats)

    float by1 = boxes[gn * 4 + 0];
    float bx1 = boxes[gn * 4 + 1];
    float by2 = boxes[gn * 4 + 2];
    float bx2 = boxes[gn * 4 + 3];

    float ty = (float)y  / 31.0f;
    float tx = (float)px / 31.0f;
    float ys = (by1 + ty * (by2 - by1)) * 191.0f;
    float xs = (bx1 + tx * (bx2 - bx1)) * 191.0f;
    float y0f = fminf(fmaxf(floorf(ys), 0.0f), 191.0f);
    float x0f = fminf(fmaxf(floorf(xs), 0.0f), 191.0f);
    float wy = ys - y0f, wx = xs - x0f;
    int y0i = (int)y0f, x0i = (int)x0f;
    int y1i = min(y0i + 1, 191), x1i = min(x0i + 1, 191);

    const float* fb = feat + (size_t)box_ids[gn] * (HH * WW * CC);
    const float* p00 = fb + ((size_t)y0i * WW + x0i) * CC + c0;
    const float* p01 = fb + ((size_t)y0i * WW + x1i) * CC + c0;
    const float* p10 = fb + ((size_t)y1i * WW + x0i) * CC + c0;
    const float* p11 = fb + ((size_t)y1i * WW + x1i) * CC + c0;

    unsigned int r[4];
#pragma unroll
    for (int h = 0; h < 2; h++) {
        float4 v00 = *(const float4*)(p00 + 4 * h);
        float4 v01 = *(const float4*)(p01 + 4 * h);
        float4 v10 = *(const float4*)(p10 + 4 * h);
        float4 v11 = *(const float4*)(p11 + 4 * h);
        const float* a00 = (const float*)&v00;
        const float* a01 = (const float*)&v01;
        const float* a10 = (const float*)&v10;
        const float* a11 = (const float*)&v11;
#pragma unroll
        for (int i = 0; i < 4; i++) {
            float top = a00[i] + wx * (a01[i] - a00[i]);
            float bot = a10[i] + wx * (a11[i] - a10[i]);
            float v = top + wy * (bot - top);
            unsigned short b = f2bf(v);
            int e = 4 * h + i;            // element 0..7
            if (e & 1) r[e >> 1] |= ((unsigned int)b << 16);
            else       r[e >> 1]  = (unsigned int)b;
        }
    }
    *(uint4*)(out + (((size_t)nl * 32 + y) * 32 + px) * CC + c0) = *(uint4*)r;
}

// ---------------------------------------------------------------------------
// 3x3 SAME conv, 64->64 ch, + ReLU, bf16 in/out, f32 accum via MFMA 16x16x32.
// Block: one box x 8-row tile. 4 waves; wave w computes rows 2w,2w+1 (64 px) x 64 oc.
// LDS input tile [10 rows][32 px][64 ch], x-stride padded to 72 elems.
// Weights read from pre-transposed global WT (L2-resident, coalesced 16B/lane).
// ---------------------------------------------------------------------------
__global__ __launch_bounds__(256, 3) void conv3x3_kernel(const unsigned short* __restrict__ in,
                                                         const unsigned short* __restrict__ wt,
                                                         const float* __restrict__ bias,
                                                         unsigned short* __restrict__ out) {
    __shared__ unsigned short s_in[10 * 32 * 72];   // 46080 B

    int nl = blockIdx.y;
    int y0 = blockIdx.x << 3;
    int t = threadIdx.x;
    int wave = t >> 6, lane = t & 63;
    int quad = lane >> 4, mcol = lane & 15;

    // stage input rows y0-1 .. y0+8 (zero rows outside [0,32))
    {
        int px = t >> 3, cc = (t & 7) << 3;
        const unsigned short* src = in + (((size_t)nl * 32) * 32 + px) * 64 + cc;
#pragma unroll
        for (int r = 0; r < 10; r++) {
            int gy = y0 + r - 1;
            uint4 v = {0, 0, 0, 0};
            if (gy >= 0 && gy < 32) v = *(const uint4*)(src + (size_t)gy * 32 * 64);
            *(uint4*)(s_in + (r * 32 + px) * 72 + cc) = v;
        }
    }
    __syncthreads();

    f32x4 acc[4][4];
#pragma unroll
    for (int nt = 0; nt < 4; nt++) {
        float bv = bias[(nt << 4) + mcol];
#pragma unroll
        for (int mi = 0; mi < 4; mi++) acc[mi][nt] = (f32x4){bv, bv, bv, bv};
    }

    int r0 = wave << 1;
#pragma unroll
    for (int dy = 0; dy < 3; dy++) {
#pragma unroll
        for (int dx = 0; dx < 3; dx++) {
            int tap = dy * 3 + dx;
#pragma unroll
            for (int kc = 0; kc < 2; kc++) {
                uint4 bfr[4];
#pragma unroll
                for (int nt = 0; nt < 4; nt++)
                    bfr[nt] = *(const uint4*)(wt + ((((tap * 2 + kc) * 4 + nt) * 64 + lane) << 3));
                uint4 afr[4];
#pragma unroll
                for (int mi = 0; mi < 4; mi++) {
                    int xs = ((mi & 1) << 4) + mcol + dx - 1;
                    uint4 a = {0, 0, 0, 0};
                    if (xs >= 0 && xs < 32)
                        a = *(const uint4*)(s_in + ((r0 + (mi >> 1) + dy) * 32 + xs) * 72 +
                                            (kc << 5) + (quad << 3));
                    afr[mi] = a;
                }
#pragma unroll
                for (int mi = 0; mi < 4; mi++)
#pragma unroll
                    for (int nt = 0; nt < 4; nt++)
                        acc[mi][nt] = __builtin_amdgcn_mfma_f32_16x16x32_bf16(
                            __builtin_bit_cast(bf16x8, afr[mi]),
                            __builtin_bit_cast(bf16x8, bfr[nt]), acc[mi][nt], 0, 0, 0);
            }
        }
    }

    // epilogue: D element (m = quad*4+reg, oc = nt*16 + mcol); ReLU; bf16 store
#pragma unroll
    for (int mi = 0; mi < 4; mi++) {
        int yy = y0 + r0 + (mi >> 1);
        int xb = ((mi & 1) << 4) + (quad << 2);
#pragma unroll
        for (int reg = 0; reg < 4; reg++) {
            unsigned short* op = out + (((size_t)nl * 32 + yy) * 32 + (xb + reg)) * 64 + mcol;
#pragma unroll
            for (int nt = 0; nt < 4; nt++) {
                float v = fmaxf(acc[mi][nt][reg], 0.0f);
                op[nt << 4] = f2bf(v);
            }
        }
    }
}

// ---------------------------------------------------------------------------
// Final 3x3 VALID conv via MFMA, selected class only (B cols padded to 16).
// Same structure as conv3x3: block = (8-out-row tile, box), 4 waves, LDS-staged
// act rows y0..y0+9. Epilogue: lanes with mcol==cls write f32 out [N][30][30].
// ---------------------------------------------------------------------------
__global__ __launch_bounds__(256, 3) void outconv_mfma_kernel(const unsigned short* __restrict__ in,
                                                              const unsigned short* __restrict__ wto,
                                                              const float* __restrict__ ob,
                                                              const int* __restrict__ cls,
                                                              float* __restrict__ out, int n0) {
    __shared__ unsigned short s_act[10 * 32 * 72];   // 46080 B

    int nl = blockIdx.y;
    int y0 = blockIdx.x << 3;
    int t = threadIdx.x;
    int wave = t >> 6, lane = t & 63;
    int quad = lane >> 4, mcol = lane & 15;

    // stage act rows y0 .. y0+9 (zero rows >= 32)
    {
        int px = t >> 3, cc = (t & 7) << 3;
        const unsigned short* src = in + (((size_t)nl * 32) * 32 + px) * 64 + cc;
#pragma unroll
        for (int r = 0; r < 10; r++) {
            int gy = y0 + r;
            uint4 v = {0, 0, 0, 0};
            if (gy < 32) v = *(const uint4*)(src + (size_t)gy * 32 * 64);
            *(uint4*)(s_act + (r * 32 + px) * 72 + cc) = v;
        }
    }
    __syncthreads();

    f32x4 acc[4];
#pragma unroll
    for (int mi = 0; mi < 4; mi++) acc[mi] = (f32x4){0.f, 0.f, 0.f, 0.f};

    int r0 = wave << 1;
#pragma unroll
    for (int dy = 0; dy < 3; dy++) {
#pragma unroll
        for (int dx = 0; dx < 3; dx++) {
            int tap = dy * 3 + dx;
#pragma unroll
            for (int kc = 0; kc < 2; kc++) {
                uint4 bfr = *(const uint4*)(wto + (((tap * 2 + kc) * 64 + lane) << 3));
#pragma unroll
                for (int mi = 0; mi < 4; mi++) {
                    int xs = ((mi & 1) << 4) + mcol + dx;     // VALID: 0..33
                    if (xs > 31) xs = 31;                     // clamped lanes feed x>=30 (discarded)
                    uint4 a = *(const uint4*)(s_act + ((r0 + (mi >> 1) + dy) * 32 + xs) * 72 +
                                              (kc << 5) + (quad << 3));
                    acc[mi] = __builtin_amdgcn_mfma_f32_16x16x32_bf16(
                        __builtin_bit_cast(bf16x8, a),
                        __builtin_bit_cast(bf16x8, bfr), acc[mi], 0, 0, 0);
                }
            }
        }
    }

    int gn = n0 + nl;
    int oc = cls[gn];
    if (mcol == oc) {
        float bias = ob[oc];
#pragma unroll
        for (int mi = 0; mi < 4; mi++) {
            int yy = y0 + r0 + (mi >> 1);
            int xb = ((mi & 1) << 4) + (quad << 2);
            if (yy < 30) {
#pragma unroll
                for (int reg = 0; reg < 4; reg++) {
                    int x = xb + reg;
                    if (x < 30)
                        out[(size_t)gn * 900 + yy * 30 + x] = acc[mi][reg] + bias;
                }
            }
        }
    }
}

// ---------------------------------------------------------------------------
extern "C" void kernel_launch(void* const* d_in, const int* in_sizes, int n_in,
                              void* d_out, int out_size, void* d_ws, size_t ws_size,
                              hipStream_t stream) {
    const float* feat    = (const float*)d_in[0];
    const float* boxes   = (const float*)d_in[1];
    const int*   box_ids = (const int*)d_in[2];
    const int*   cls     = (const int*)d_in[3];
    const float* c1w     = (const float*)d_in[4];
    const float* c1b     = (const float*)d_in[5];
    const float* c2w     = (const float*)d_in[6];
    const float* c2b     = (const float*)d_in[7];
    const float* ow      = (const float*)d_in[8];
    const float* ob      = (const float*)d_in[9];

    unsigned short* wt1  = (unsigned short*)d_ws;
    unsigned short* wt2  = wt1 + 36864;
    unsigned short* wto  = wt2 + 36864;
    unsigned short* bufs = wto + 9216;

    // chunk boxes so two bf16 [nc][32][32][64] buffers fit in ws (deterministic)
    size_t wt_bytes = (size_t)(36864 * 2 + 9216) * 2;
    size_t avail = (ws_size > wt_bytes) ? (ws_size - wt_bytes) / 2 : 0;
    size_t per_box = (size_t)32 * 32 * 64 * 2;
    int nc = (int)(avail / per_box);
    if (nc >= NB) nc = NB;
    else {
        int p = 1;
        while (p * 2 <= nc) p *= 2;
        nc = (p < 1) ? 1 : p;
    }

    wt_kernel<<<144, 256, 0, stream>>>(c1w, wt1);
    wt_kernel<<<144, 256, 0, stream>>>(c2w, wt2);
    wto_kernel<<<36, 256, 0, stream>>>(ow, wto);

    unsigned short* bufA = bufs;
    unsigned short* bufB = bufs + (size_t)nc * 65536;

    for (int nn0 = 0; nn0 < NB; nn0 += nc) {
        int cur = (NB - nn0 < nc) ? (NB - nn0) : nc;
        crop_kernel<<<cur * 32, 256, 0, stream>>>(feat, boxes, box_ids, bufA, nn0);
        conv3x3_kernel<<<dim3(4, cur), 256, 0, stream>>>(bufA, wt1, c1b, bufB);
        conv3x3_kernel<<<dim3(4, cur), 256, 0, stream>>>(bufB, wt2, c2b, bufA);
        outconv_mfma_kernel<<<dim3(4, cur), 256, 0, stream>>>(bufA, wto, ob, cls,
                                                              (float*)d_out, nn0);
    }
}